// Round 14
// baseline (205.637 us; speedup 1.0000x reference)
//
#include <hip/hip_runtime.h>
#include <math.h>

// SelfSimilarity (fused):
// out[b,n,m] = softmax_m( -(|x_n|^2+|x_m|^2-2 x_n.x_m)/T )
//            = e_m / sum_m e_m,   e_m = exp2( kexp*dot(x_n,x_m) - 0.5*kexp*|x_m|^2 )
// prep: bf16 hi/lo rows (xhi/xlo) + kexp-scaled hi/lo cols (xhs/xls) + csq.
// ONE fused kernel per 16 output rows (block-local softmax, no cross-block parts):
//   sweep1: single-product ah.bh rowsums over all 4096 cols (2 MFMA/tile)
//   diag fix: sum' = sum - e1d(bf16 replay) + exp2(-csq[R])  (R7-proven)
//   sweep2: 3-product (6 MFMA/tile), rinv folded, swizzled LDS stage ->
//           linear NT f32x4 stores.
// Rationale (R11 PMC + R7-R13 nulls): both phases latency-bound with all pipes
// idle; splitting into 2 kernels serializes them behind a full-device drain.
// Fusing lets resident blocks overlap sweep1(compute-only) with sweep2(stores)
// and removes one drain. 1024 blocks all co-resident (~8.4 KB LDS, VGPR~64).

constexpr int NB = 4;
constexpr int N = 4096;
constexpr int D = 64;
constexpr float TEMP = 13.544f;
constexpr int TM = 16;                   // rows per block
constexpr int NW = 4;
constexpr int THREADS = 256;
constexpr int TILES = N / (NW * 16);     // 64 col-tiles (each 64 cols) per block

typedef __attribute__((ext_vector_type(8))) short bf16x8;
typedef __attribute__((ext_vector_type(4))) float f32x4;

__device__ __forceinline__ unsigned short f2bf(float f) {
    unsigned int u = __builtin_bit_cast(unsigned int, f);
    u += 0x7FFFu + ((u >> 16) & 1u);   // RNE
    return (unsigned short)(u >> 16);
}
__device__ __forceinline__ float bf2f(unsigned short h) {
    return __builtin_bit_cast(float, (unsigned int)h << 16);
}

// ---------------- Pre-pass: convert + squares ----------------
__global__ __launch_bounds__(THREADS)
void prep_kernel(const float* __restrict__ x,
                 short* __restrict__ xhi, short* __restrict__ xlo,
                 short* __restrict__ xhs, short* __restrict__ xls,
                 float* __restrict__ csq) {
    const int t = threadIdx.x;
    const int lane = t & 63, w = t >> 6;
    const int row = blockIdx.x * 32 + w * 8 + (lane >> 3);
    const int seg = lane & 7;
    const float S = 2.0f * 1.4426950408889634f / TEMP;   // kexp

    const float* p = x + (size_t)row * D + seg * 8;
    const float4 u = *reinterpret_cast<const float4*>(p);
    const float4 v = *reinterpret_cast<const float4*>(p + 4);
    float e[8] = {u.x, u.y, u.z, u.w, v.x, v.y, v.z, v.w};

    float sq = 0.f;
    #pragma unroll
    for (int j = 0; j < 8; ++j) sq += e[j] * e[j];
    sq += __shfl_xor(sq, 1, 64);
    sq += __shfl_xor(sq, 2, 64);
    sq += __shfl_xor(sq, 4, 64);

    bf16x8 h, l, hs, ls;
    #pragma unroll
    for (int j = 0; j < 8; ++j) {
        const unsigned short hb = f2bf(e[j]);
        h[j] = (short)hb;
        l[j] = (short)f2bf(e[j] - bf2f(hb));
        const float es = e[j] * S;
        const unsigned short hsb = f2bf(es);
        hs[j] = (short)hsb;
        ls[j] = (short)f2bf(es - bf2f(hsb));
    }
    const int off = row * D + seg * 8;
    *reinterpret_cast<bf16x8*>(xhi + off) = h;
    *reinterpret_cast<bf16x8*>(xlo + off) = l;
    *reinterpret_cast<bf16x8*>(xhs + off) = hs;
    *reinterpret_cast<bf16x8*>(xls + off) = ls;
    if (seg == 0) csq[row] = -0.5f * S * sq;
}

// ---------------- Fused: rowsum sweep + normalize/store sweep ----------------
__global__ __launch_bounds__(THREADS)
void fused_kernel(const short* __restrict__ xhi, const short* __restrict__ xlo,
                  const short* __restrict__ xhs, const short* __restrict__ xls,
                  const float* __restrict__ csq, float* __restrict__ out) {
    const int b = blockIdx.y;
    const int row0 = blockIdx.x * TM;
    const int t = threadIdx.x;
    const int w = t >> 6, lane = t & 63;
    const int lr = lane & 15, kg = lane >> 4;
    const int rbase = b * N;

    // persistent row-side fragments (MFMA B operand), rows row0 + lr
    bf16x8 bh[2], bl[2];
    {
        const int r = rbase + row0 + lr;
        const short* ph = xhi + (size_t)r * D + kg * 8;
        const short* pl = xlo + (size_t)r * D + kg * 8;
        #pragma unroll
        for (int kt = 0; kt < 2; ++kt) {
            bh[kt] = *reinterpret_cast<const bf16x8*>(ph + kt * 32);
            bl[kt] = *reinterpret_cast<const bf16x8*>(pl + kt * 32);
        }
    }

    __shared__ float red[NW][TM];
    __shared__ float rlds[TM];
    __shared__ float buf[2][1024];   // 2 x 4KB staging (double-buffered)

    // ---- sweep 1: rowsums, single product (2 MFMA / 64-col tile) ----
    float rs = 0.f;
    #pragma unroll 2
    for (int j = 0; j < TILES; ++j) {
        const int c = rbase + j * 64 + w * 16;
        const short* pa = xhs + (size_t)(c + lr) * D + kg * 8;
        const bf16x8 ah0 = *reinterpret_cast<const bf16x8*>(pa);
        const bf16x8 ah1 = *reinterpret_cast<const bf16x8*>(pa + 32);
        f32x4 acc = *reinterpret_cast<const f32x4*>(csq + c + kg * 4);
        acc = __builtin_amdgcn_mfma_f32_16x16x32_bf16(ah0, bh[0], acc, 0, 0, 0);
        acc = __builtin_amdgcn_mfma_f32_16x16x32_bf16(ah1, bh[1], acc, 0, 0, 0);
        #pragma unroll
        for (int q = 0; q < 4; ++q) rs += __builtin_amdgcn_exp2f(acc[q]);
    }
    // lanes sharing an output row differ in kg (lane>>4)
    rs += __shfl_xor(rs, 16, 64);
    rs += __shfl_xor(rs, 32, 64);
    if (lane < 16) red[w][lr] = rs;
    __syncthreads();

    // ---- combine + exact diagonal correction (replay sweep1's bf16 diag) ----
    if (t < TM) {
        const float sum = (red[0][t] + red[1][t]) + (red[2][t] + red[3][t]);
        const int R = rbase + row0 + t;
        float s1 = 0.f;
        #pragma unroll
        for (int kc = 0; kc < D / 8; ++kc) {
            const bf16x8 hsv = *reinterpret_cast<const bf16x8*>(xhs + (size_t)R * D + kc * 8);
            const bf16x8 hv  = *reinterpret_cast<const bf16x8*>(xhi + (size_t)R * D + kc * 8);
            #pragma unroll
            for (int j = 0; j < 8; ++j)
                s1 += bf2f((unsigned short)hsv[j]) * bf2f((unsigned short)hv[j]);
        }
        const float cR = csq[R];
        const float e1d = __builtin_amdgcn_exp2f(s1 + cR);
        const float etd = __builtin_amdgcn_exp2f(-cR);   // true rescaled diagonal
        rlds[t] = 1.0f / (sum - e1d + etd);
    }
    __syncthreads();
    const float rinv = rlds[lr];

    // ---- sweep 2: 3-product recompute + normalized store ----
    #pragma unroll 2
    for (int j = 0; j < TILES; ++j) {
        const int c = rbase + j * 64 + w * 16;
        const short* pa_h = xhs + (size_t)(c + lr) * D + kg * 8;
        const short* pa_l = xls + (size_t)(c + lr) * D + kg * 8;
        const bf16x8 ah0 = *reinterpret_cast<const bf16x8*>(pa_h);
        const bf16x8 ah1 = *reinterpret_cast<const bf16x8*>(pa_h + 32);
        const bf16x8 al0 = *reinterpret_cast<const bf16x8*>(pa_l);
        const bf16x8 al1 = *reinterpret_cast<const bf16x8*>(pa_l + 32);
        f32x4 acc = *reinterpret_cast<const f32x4*>(csq + c + kg * 4);

        acc = __builtin_amdgcn_mfma_f32_16x16x32_bf16(ah0, bh[0], acc, 0, 0, 0);
        acc = __builtin_amdgcn_mfma_f32_16x16x32_bf16(ah1, bh[1], acc, 0, 0, 0);
        acc = __builtin_amdgcn_mfma_f32_16x16x32_bf16(ah0, bl[0], acc, 0, 0, 0);
        acc = __builtin_amdgcn_mfma_f32_16x16x32_bf16(ah1, bl[1], acc, 0, 0, 0);
        acc = __builtin_amdgcn_mfma_f32_16x16x32_bf16(al0, bh[0], acc, 0, 0, 0);
        acc = __builtin_amdgcn_mfma_f32_16x16x32_bf16(al1, bh[1], acc, 0, 0, 0);

        f32x4 o;
        #pragma unroll
        for (int q = 0; q < 4; ++q)
            o[q] = __builtin_amdgcn_exp2f(acc[q]) * rinv;

        // conflict-free swizzled stage: slot4 = lr*16 + (col4 ^ lr), col4 = w*4+kg
        float* bj = buf[j & 1];
        *reinterpret_cast<f32x4*>(bj + (lr * 16 + ((w * 4 + kg) ^ lr)) * 4) = o;
        __syncthreads();
        // flush: thread t -> row t>>4, col4 t&15 (wave = 4 rows x 64 cols, 1KB)
        const int row = t >> 4, col4 = t & 15;
        const f32x4 v = *reinterpret_cast<const f32x4*>(
            bj + (row * 16 + (col4 ^ row)) * 4);
        __builtin_nontemporal_store(v, reinterpret_cast<f32x4*>(
            out + (size_t)(rbase + row0 + row) * N + j * 64 + col4 * 4));
    }
}

extern "C" void kernel_launch(void* const* d_in, const int* in_sizes, int n_in,
                              void* d_out, int out_size, void* d_ws, size_t ws_size,
                              hipStream_t stream) {
    const float* x = (const float*)d_in[0];
    float* out = (float*)d_out;

    constexpr int NE = NB * N * D;       // 1048576 elements
    short* xhi = (short*)d_ws;
    short* xlo = xhi + NE;
    short* xhs = xlo + NE;
    short* xls = xhs + NE;
    float* csq = (float*)(xls + NE);     // NB*N floats

    hipLaunchKernelGGL(prep_kernel, dim3(NB * N / 32), dim3(THREADS), 0, stream,
                       x, xhi, xlo, xhs, xls, csq);

    dim3 grid(N / TM, NB);               // 256 x 4 = 1024 blocks, all co-resident
    hipLaunchKernelGGL(fused_kernel, grid, dim3(THREADS), 0, stream,
                       xhi, xlo, xhs, xls, csq, out);
}

// Round 15
// 158.647 us; speedup vs baseline: 1.2962x; 1.2962x over previous
//
#include <hip/hip_runtime.h>
#include <math.h>

// SelfSimilarity:
// out[b,n,m] = softmax_m( -(|x_n|^2+|x_m|^2-2 x_n.x_m)/T )
//            = e_m / sum_m e_m,   e_m = exp2( kexp*dot(x_n,x_m) - 0.5*kexp*|x_m|^2 )
// phase1 (rowsum): SINGLE product ah.bh; diag corrected: sum - e1d + exp2(-csq).
// phase2 (store): 3-product ah.bh+ah.bl+al.bh; DIRECT fragment f32x4 stores.
//
// R15 hypothesis (from R7/R9/R11/R14 data): wall time ~ #tile-iterations x
// ~600-700cy serial chain per iter (load->dependent MFMAs->exp), all pipes idle.
// Fix: 4 col-groups (64 cols) per wave-iteration -> 4 iters instead of 16, with
// 8/24 INDEPENDENT interleaved MFMA chains per iter filling the latency shadow.
// p2 drops LDS staging/barriers entirely (fire-and-forget scattered stores).

constexpr int NB = 4;
constexpr int N = 4096;
constexpr int D = 64;
constexpr float TEMP = 13.544f;
constexpr int CSPL = 4;
constexpr int COLS = N / CSPL;           // 1024 cols per block
constexpr int TMB = 32;                  // rows per block
constexpr int NW = 4;
constexpr int THREADS = 256;
constexpr int CG = 4;                    // col-groups (16 cols) per wave per iter
constexpr int ITERS = COLS / (NW * CG * 16);  // 4 iterations

typedef __attribute__((ext_vector_type(8))) short bf16x8;
typedef __attribute__((ext_vector_type(4))) float f32x4;

__device__ __forceinline__ unsigned short f2bf(float f) {
    unsigned int u = __builtin_bit_cast(unsigned int, f);
    u += 0x7FFFu + ((u >> 16) & 1u);   // RNE
    return (unsigned short)(u >> 16);
}
__device__ __forceinline__ float bf2f(unsigned short h) {
    return __builtin_bit_cast(float, (unsigned int)h << 16);
}

// ---------------- Pre-pass: convert + squares ----------------
__global__ __launch_bounds__(THREADS)
void prep_kernel(const float* __restrict__ x,
                 short* __restrict__ xhi, short* __restrict__ xlo,
                 short* __restrict__ xhs, short* __restrict__ xls,
                 float* __restrict__ csq) {
    const int t = threadIdx.x;
    const int lane = t & 63, w = t >> 6;
    const int row = blockIdx.x * 32 + w * 8 + (lane >> 3);
    const int seg = lane & 7;
    const float S = 2.0f * 1.4426950408889634f / TEMP;   // kexp

    const float* p = x + (size_t)row * D + seg * 8;
    const float4 u = *reinterpret_cast<const float4*>(p);
    const float4 v = *reinterpret_cast<const float4*>(p + 4);
    float e[8] = {u.x, u.y, u.z, u.w, v.x, v.y, v.z, v.w};

    float sq = 0.f;
    #pragma unroll
    for (int j = 0; j < 8; ++j) sq += e[j] * e[j];
    sq += __shfl_xor(sq, 1, 64);
    sq += __shfl_xor(sq, 2, 64);
    sq += __shfl_xor(sq, 4, 64);

    bf16x8 h, l, hs, ls;
    #pragma unroll
    for (int j = 0; j < 8; ++j) {
        const unsigned short hb = f2bf(e[j]);
        h[j] = (short)hb;
        l[j] = (short)f2bf(e[j] - bf2f(hb));
        const float es = e[j] * S;
        const unsigned short hsb = f2bf(es);
        hs[j] = (short)hsb;
        ls[j] = (short)f2bf(es - bf2f(hsb));
    }
    const int off = row * D + seg * 8;
    *reinterpret_cast<bf16x8*>(xhi + off) = h;
    *reinterpret_cast<bf16x8*>(xlo + off) = l;
    *reinterpret_cast<bf16x8*>(xhs + off) = hs;
    *reinterpret_cast<bf16x8*>(xls + off) = ls;
    if (seg == 0) csq[row] = -0.5f * S * sq;
}

// ---------------- Main sweep: rowsum / normalize+store ----------------
template<bool STORE>
__global__ __launch_bounds__(THREADS, 2)
void sweep_kernel(const short* __restrict__ xhi, const short* __restrict__ xlo,
                  const short* __restrict__ xhs, const short* __restrict__ xls,
                  const float* __restrict__ csq, float* __restrict__ parts,
                  float* __restrict__ out) {
    const int b = blockIdx.y;
    const int s = blockIdx.z;
    const int row0 = blockIdx.x * TMB;
    const int t = threadIdx.x;
    const int w = t >> 6, lane = t & 63;
    const int lr = lane & 15, kg = lane >> 4;
    const int rbase = b * N;

    // persistent row-side fragments (MFMA B operand), rows row0 + 16*i + lr
    bf16x8 bh[2][2], bl[2][2];
    #pragma unroll
    for (int i = 0; i < 2; ++i) {
        const int r = rbase + row0 + 16 * i + lr;
        const short* ph = xhi + (size_t)r * D + kg * 8;
        #pragma unroll
        for (int kt = 0; kt < 2; ++kt)
            bh[i][kt] = *reinterpret_cast<const bf16x8*>(ph + kt * 32);
        if (STORE) {
            const short* pl = xlo + (size_t)r * D + kg * 8;
            #pragma unroll
            for (int kt = 0; kt < 2; ++kt)
                bl[i][kt] = *reinterpret_cast<const bf16x8*>(pl + kt * 32);
        }
    }

    __shared__ float red[NW][TMB];
    __shared__ float rlds[TMB];

    float rinv0 = 0.f, rinv1 = 0.f;
    if (STORE) {
        if (t < TMB) {
            const int R = rbase + row0 + t;
            const f32x4 pp = *reinterpret_cast<const f32x4*>(parts + (size_t)R * CSPL);
            const float sum = (pp[0] + pp[1]) + (pp[2] + pp[3]);
            // replay phase1's single-product diag term in matching bf16 arithmetic
            float s1 = 0.f;
            #pragma unroll
            for (int kc = 0; kc < D / 8; ++kc) {
                const bf16x8 hsv = *reinterpret_cast<const bf16x8*>(xhs + (size_t)R * D + kc * 8);
                const bf16x8 hv  = *reinterpret_cast<const bf16x8*>(xhi + (size_t)R * D + kc * 8);
                #pragma unroll
                for (int j = 0; j < 8; ++j)
                    s1 += bf2f((unsigned short)hsv[j]) * bf2f((unsigned short)hv[j]);
            }
            const float cR = csq[R];
            const float e1d = __builtin_amdgcn_exp2f(s1 + cR);
            const float etd = __builtin_amdgcn_exp2f(-cR);   // true rescaled diagonal
            rlds[t] = 1.0f / (sum - e1d + etd);
        }
        __syncthreads();
        rinv0 = rlds[lr];
        rinv1 = rlds[16 + lr];
    }

    float rs0 = 0.f, rs1 = 0.f;

    #pragma unroll 1
    for (int j = 0; j < ITERS; ++j) {
        // wave w covers cols [base, base+64) this iteration
        const int base = s * COLS + j * (NW * CG * 16) + w * (CG * 16);

        // ---- gather operands for 4 col-groups (independent) ----
        bf16x8 ah[CG][2], al[CG][2];
        f32x4 acc0[CG], acc1[CG];
        #pragma unroll
        for (int cg = 0; cg < CG; ++cg) {
            const int c = rbase + base + cg * 16;
            const short* pa = xhs + (size_t)(c + lr) * D + kg * 8;
            ah[cg][0] = *reinterpret_cast<const bf16x8*>(pa);
            ah[cg][1] = *reinterpret_cast<const bf16x8*>(pa + 32);
            if (STORE) {
                const short* pb = xls + (size_t)(c + lr) * D + kg * 8;
                al[cg][0] = *reinterpret_cast<const bf16x8*>(pb);
                al[cg][1] = *reinterpret_cast<const bf16x8*>(pb + 32);
            }
            const f32x4 c4 = *reinterpret_cast<const f32x4*>(csq + c + kg * 4);
            acc0[cg] = c4;
            acc1[cg] = c4;
        }

        // ---- interleaved MFMA chains (8 or 24 independent streams) ----
        #pragma unroll
        for (int kt = 0; kt < 2; ++kt)
            #pragma unroll
            for (int cg = 0; cg < CG; ++cg) {
                acc0[cg] = __builtin_amdgcn_mfma_f32_16x16x32_bf16(ah[cg][kt], bh[0][kt], acc0[cg], 0, 0, 0);
                acc1[cg] = __builtin_amdgcn_mfma_f32_16x16x32_bf16(ah[cg][kt], bh[1][kt], acc1[cg], 0, 0, 0);
            }
        if (STORE) {
            #pragma unroll
            for (int kt = 0; kt < 2; ++kt)
                #pragma unroll
                for (int cg = 0; cg < CG; ++cg) {
                    acc0[cg] = __builtin_amdgcn_mfma_f32_16x16x32_bf16(ah[cg][kt], bl[0][kt], acc0[cg], 0, 0, 0);
                    acc1[cg] = __builtin_amdgcn_mfma_f32_16x16x32_bf16(ah[cg][kt], bl[1][kt], acc1[cg], 0, 0, 0);
                }
            #pragma unroll
            for (int kt = 0; kt < 2; ++kt)
                #pragma unroll
                for (int cg = 0; cg < CG; ++cg) {
                    acc0[cg] = __builtin_amdgcn_mfma_f32_16x16x32_bf16(al[cg][kt], bh[0][kt], acc0[cg], 0, 0, 0);
                    acc1[cg] = __builtin_amdgcn_mfma_f32_16x16x32_bf16(al[cg][kt], bh[1][kt], acc1[cg], 0, 0, 0);
                }
        }

        // ---- epilogue ----
        if (STORE) {
            #pragma unroll
            for (int cg = 0; cg < CG; ++cg) {
                f32x4 o0, o1;
                #pragma unroll
                for (int q = 0; q < 4; ++q) {
                    o0[q] = __builtin_amdgcn_exp2f(acc0[cg][q]) * rinv0;
                    o1[q] = __builtin_amdgcn_exp2f(acc1[cg][q]) * rinv1;
                }
                const int col = base + cg * 16 + kg * 4;
                float* p0 = out + (size_t)(rbase + row0 + lr) * N + col;
                float* p1 = out + (size_t)(rbase + row0 + 16 + lr) * N + col;
                __builtin_nontemporal_store(o0, reinterpret_cast<f32x4*>(p0));
                __builtin_nontemporal_store(o1, reinterpret_cast<f32x4*>(p1));
            }
        } else {
            #pragma unroll
            for (int cg = 0; cg < CG; ++cg)
                #pragma unroll
                for (int q = 0; q < 4; ++q) {
                    rs0 += __builtin_amdgcn_exp2f(acc0[cg][q]);
                    rs1 += __builtin_amdgcn_exp2f(acc1[cg][q]);
                }
        }
    }

    if (!STORE) {
        // lanes sharing an output row differ in kg (lane>>4)
        rs0 += __shfl_xor(rs0, 16, 64); rs0 += __shfl_xor(rs0, 32, 64);
        rs1 += __shfl_xor(rs1, 16, 64); rs1 += __shfl_xor(rs1, 32, 64);
        if (lane < 16) { red[w][lr] = rs0; red[w][16 + lr] = rs1; }
        __syncthreads();
        if (t < TMB) {
            const float sum = (red[0][t] + red[1][t]) + (red[2][t] + red[3][t]);
            parts[(size_t)(rbase + row0 + t) * CSPL + s] = sum;
        }
    }
}

extern "C" void kernel_launch(void* const* d_in, const int* in_sizes, int n_in,
                              void* d_out, int out_size, void* d_ws, size_t ws_size,
                              hipStream_t stream) {
    const float* x = (const float*)d_in[0];
    float* out = (float*)d_out;

    constexpr int NE = NB * N * D;       // 1048576 elements
    short* xhi = (short*)d_ws;
    short* xlo = xhi + NE;
    short* xhs = xlo + NE;
    short* xls = xhs + NE;
    float* csq = (float*)(xls + NE);     // NB*N floats
    float* parts = csq + NB * N;         // NB*N*CSPL floats

    hipLaunchKernelGGL(prep_kernel, dim3(NB * N / 32), dim3(THREADS), 0, stream,
                       x, xhi, xlo, xhs, xls, csq);

    dim3 grid(N / TMB, NB, CSPL);        // 128 x 4 x 4 = 2048 blocks
    hipLaunchKernelGGL((sweep_kernel<false>), grid, dim3(THREADS), 0, stream,
                       xhi, xlo, xhs, xls, csq, parts, out);
    hipLaunchKernelGGL((sweep_kernel<true>), grid, dim3(THREADS), 0, stream,
                       xhi, xlo, xhs, xls, csq, parts, out);
}